// Round 2
// baseline (462.574 us; speedup 1.0000x reference)
//
#include <hip/hip_runtime.h>
#include <cstdint>
#include <cstddef>

// Problem constants (fixed by setup_inputs)
constexpr int Bn = 64;     // batch
constexpr int Nn = 1024;   // nodes per graph
constexpr int Dn = 1024;   // input feature dim
constexpr int Cn = 128;    // hidden channels
constexpr int En = 16384;  // edges per graph

// ---------------- workspace layout (fixed part) ----------------
// 0       g       32768 B   (B x C floats: e_b @ W_conv)
// 32768   indeg   4096 B
// 36864   meta    16 B      (meta[0] = int64-detection flag)
// 40960   offs    8192 B    (needs (Nn+1)*4)
// 49152   cursor  4096 B
// 53248   ssrc    65536 B
// 118784  heap -> ping-pong h buffers (G*N*C floats each)
constexpr size_t WS_FIXED = 118784;

__global__ void k_zero(int* __restrict__ p, int n) {
    int i = blockIdx.x * 256 + threadIdx.x;
    if (i < n) p[i] = 0;
}

// Detect whether edge_index arrived as int64 (viewed as int32 pairs) or int32.
// Values are in [0,1024), so int64 layout => every odd 32-bit word is 0.
__global__ void k_detect(const int* __restrict__ ei32, int* __restrict__ flag) {
    __shared__ int sh;
    if (threadIdx.x == 0) sh = 0;
    __syncthreads();
    int i = blockIdx.x * 256 + threadIdx.x;   // [0, 2*En/2) = [0,16384)
    int v = ei32[2 * i + 1];
    if (v) atomicOr(&sh, 1);
    __syncthreads();
    if (threadIdx.x == 0 && sh) atomicOr(flag, 1);   // flag!=0 => genuine int32 data
}

__global__ void k_hist(const int* __restrict__ ei32, const int* __restrict__ flag,
                       int* __restrict__ indeg) {
    int e = blockIdx.x * 256 + threadIdx.x;
    if (e >= En) return;
    bool i64 = (flag[0] == 0);
    int idx = i64 ? 2 * (En + e) : (En + e);
    int dst = ei32[idx] & (Nn - 1);   // mask: safety net, exact for valid data
    atomicAdd(&indeg[dst], 1);
}

// single block, Nn threads: inclusive scan -> offs (exclusive, Nn+1), cursor (exclusive)
__global__ __launch_bounds__(1024) void k_scan(const int* __restrict__ indeg,
                                               int* __restrict__ offs,
                                               int* __restrict__ cursor) {
    __shared__ int tmp[Nn];
    int t = threadIdx.x;
    int v = indeg[t];
    tmp[t] = v;
    __syncthreads();
    for (int off = 1; off < Nn; off <<= 1) {
        int add = (t >= off) ? tmp[t - off] : 0;
        __syncthreads();
        tmp[t] += add;
        __syncthreads();
    }
    offs[t + 1] = tmp[t];
    if (t == 0) offs[0] = 0;
    cursor[t] = tmp[t] - v;   // exclusive prefix
}

__global__ void k_scatter(const int* __restrict__ ei32, const int* __restrict__ flag,
                          int* __restrict__ cursor, int* __restrict__ ssrc) {
    int e = blockIdx.x * 256 + threadIdx.x;
    if (e >= En) return;
    bool i64 = (flag[0] == 0);
    int sidx = i64 ? 2 * e : e;
    int didx = i64 ? 2 * (En + e) : (En + e);
    int src = ei32[sidx] & (Nn - 1);
    int dst = ei32[didx] & (Nn - 1);
    int pos = atomicAdd(&cursor[dst], 1);
    if (pos >= 0 && pos < En) ssrc[pos] = src;
}

// ---------------- embedding + g = e @ W_conv ----------------
// one block per sample b; 512 threads = 4 d-quarters x 128 channels
__global__ __launch_bounds__(512) void k_embed(const float* __restrict__ x,
                                               const float* __restrict__ We,
                                               const float* __restrict__ be,
                                               const float* __restrict__ Wc,
                                               float* __restrict__ g) {
    __shared__ float sx[Dn];
    __shared__ float sp[4 * Cn];
    __shared__ float se[Cn];
    int b = blockIdx.x, tid = threadIdx.x;
    int c = tid & 127, u = tid >> 7;
    for (int i = tid; i < Dn; i += 512) sx[i] = x[b * Dn + i];
    __syncthreads();
    float acc = 0.f;
    int d0 = u * 256;
#pragma unroll 8
    for (int d = d0; d < d0 + 256; ++d) acc += sx[d] * We[d * Cn + c];
    sp[u * Cn + c] = acc;
    __syncthreads();
    if (u == 0) {
        float e = sp[c] + sp[Cn + c] + sp[2 * Cn + c] + sp[3 * Cn + c] + be[c];
        se[c] = fmaxf(e, 0.f);
    }
    __syncthreads();
    float ga = 0.f;
    int k0 = u * 32;
#pragma unroll
    for (int k = k0; k < k0 + 32; ++k) ga += se[k] * Wc[k * Cn + c];
    sp[u * Cn + c] = ga;
    __syncthreads();
    if (u == 0) g[b * Cn + c] = sp[c] + sp[Cn + c] + sp[2 * Cn + c] + sp[3 * Cn + c];
}

// ---------------- conv #1 exploiting identical rows: h1 = relu(indeg[n]*g[b] + bc) ----------------
// g_base points at g + b0*Cn; h covers g_cur samples.
__global__ void k_h1(const float* __restrict__ g_base, const float* __restrict__ bc,
                     const int* __restrict__ indeg, float* __restrict__ h) {
    int gid = blockIdx.x * 256 + threadIdx.x;     // over g_cur*N*C/4 float4s
    int c4 = (gid & 31) * 4;
    int node = gid >> 5;                          // b_local*N + n
    int b = node >> 10, n = node & 1023;
    float deg = (float)indeg[n];
    float4 gg = *(const float4*)&g_base[b * Cn + c4];
    float4 bb = *(const float4*)&bc[c4];
    float4 r;
    r.x = fmaxf(deg * gg.x + bb.x, 0.f);
    r.y = fmaxf(deg * gg.y + bb.y, 0.f);
    r.z = fmaxf(deg * gg.z + bb.z, 0.f);
    r.w = fmaxf(deg * gg.w + bb.w, 0.f);
    *(float4*)&h[(size_t)node * Cn + c4] = r;
}

// ---------------- general conv: h_new = relu((A h) @ Wc + bc) ----------------
// grid = g_cur*32 blocks, 256 threads. swz!=0 only when g_cur==64:
// xcd = bidx&7 handles samples [xcd*8, xcd*8+8) -> per-XCD L2 working set = 4 MB.
__global__ __launch_bounds__(256, 3) void k_conv(const float* __restrict__ h,
                                                 float* __restrict__ hn,
                                                 const float* __restrict__ Wc,
                                                 const float* __restrict__ bc,
                                                 const int* __restrict__ offs,
                                                 const int* __restrict__ ssrc,
                                                 int swz) {
    __shared__ float sW[64 * Cn];   // 32 KB: half of W_conv rows
    __shared__ float sS[32 * Cn];   // 16 KB: aggregated tile
    int tid = threadIdx.x;
    int bidx = blockIdx.x;
    int b, dst0;
    if (swz) {
        int xcd = bidx & 7;
        int q = bidx >> 3;              // [0,256)
        b = xcd * 8 + (q >> 5);
        dst0 = (q & 31) * 32;
    } else {
        b = bidx >> 5;
        dst0 = (bidx & 31) * 32;
    }

    // stage W rows [0,64)
    for (int i = tid * 4; i < 64 * Cn; i += 1024)
        *(float4*)&sW[i] = *(const float4*)&Wc[i];

    // aggregation: thread (u, c) accumulates 16 dst nodes' channel c
    int c = tid & 127, u = tid >> 7;
    const float* hb = h + (size_t)b * (Nn * Cn);
    for (int t0 = 0; t0 < 16; ++t0) {
        int t = u * 16 + t0;
        int dst = dst0 + t;
        int e0 = offs[dst], e1 = offs[dst + 1];
        float acc = 0.f;
        int j = e0;
        for (; j + 3 < e1; j += 4) {
            int s0 = ssrc[j], s1 = ssrc[j + 1], s2 = ssrc[j + 2], s3 = ssrc[j + 3];
            float v0 = hb[(size_t)s0 * Cn + c];
            float v1 = hb[(size_t)s1 * Cn + c];
            float v2 = hb[(size_t)s2 * Cn + c];
            float v3 = hb[(size_t)s3 * Cn + c];
            acc += v0; acc += v1; acc += v2; acc += v3;
        }
        for (; j < e1; ++j) acc += hb[(size_t)ssrc[j] * Cn + c];
        sS[t * Cn + c] = acc;
    }
    __syncthreads();

    // 4x4 register-blocked matmul: thread (tq, cq) -> rows tb..tb+3, cols cb..cb+3
    int cq = tid & 31, tq = tid >> 5;
    int cb = cq * 4, tb = tq * 4;
    float4 acc0 = {0, 0, 0, 0}, acc1 = {0, 0, 0, 0}, acc2 = {0, 0, 0, 0}, acc3 = {0, 0, 0, 0};
#pragma unroll 4
    for (int k = 0; k < 64; ++k) {
        float4 w = *(float4*)&sW[k * Cn + cb];
        float s0 = sS[(tb + 0) * Cn + k];
        float s1 = sS[(tb + 1) * Cn + k];
        float s2 = sS[(tb + 2) * Cn + k];
        float s3 = sS[(tb + 3) * Cn + k];
        acc0.x += s0 * w.x; acc0.y += s0 * w.y; acc0.z += s0 * w.z; acc0.w += s0 * w.w;
        acc1.x += s1 * w.x; acc1.y += s1 * w.y; acc1.z += s1 * w.z; acc1.w += s1 * w.w;
        acc2.x += s2 * w.x; acc2.y += s2 * w.y; acc2.z += s2 * w.z; acc2.w += s2 * w.w;
        acc3.x += s3 * w.x; acc3.y += s3 * w.y; acc3.z += s3 * w.z; acc3.w += s3 * w.w;
    }
    __syncthreads();
    // stage W rows [64,128)
    for (int i = tid * 4; i < 64 * Cn; i += 1024)
        *(float4*)&sW[i] = *(const float4*)&Wc[64 * Cn + i];
    __syncthreads();
#pragma unroll 4
    for (int k = 0; k < 64; ++k) {
        float4 w = *(float4*)&sW[k * Cn + cb];
        int kk = k + 64;
        float s0 = sS[(tb + 0) * Cn + kk];
        float s1 = sS[(tb + 1) * Cn + kk];
        float s2 = sS[(tb + 2) * Cn + kk];
        float s3 = sS[(tb + 3) * Cn + kk];
        acc0.x += s0 * w.x; acc0.y += s0 * w.y; acc0.z += s0 * w.z; acc0.w += s0 * w.w;
        acc1.x += s1 * w.x; acc1.y += s1 * w.y; acc1.z += s1 * w.z; acc1.w += s1 * w.w;
        acc2.x += s2 * w.x; acc2.y += s2 * w.y; acc2.z += s2 * w.z; acc2.w += s2 * w.w;
        acc3.x += s3 * w.x; acc3.y += s3 * w.y; acc3.z += s3 * w.z; acc3.w += s3 * w.w;
    }

    float4 bb = *(const float4*)&bc[cb];
    float* o = hn + ((size_t)b * Nn + dst0 + tb) * Cn + cb;
    float4 r;
    r.x = fmaxf(acc0.x + bb.x, 0.f); r.y = fmaxf(acc0.y + bb.y, 0.f);
    r.z = fmaxf(acc0.z + bb.z, 0.f); r.w = fmaxf(acc0.w + bb.w, 0.f);
    *(float4*)(o + 0 * Cn) = r;
    r.x = fmaxf(acc1.x + bb.x, 0.f); r.y = fmaxf(acc1.y + bb.y, 0.f);
    r.z = fmaxf(acc1.z + bb.z, 0.f); r.w = fmaxf(acc1.w + bb.w, 0.f);
    *(float4*)(o + 1 * Cn) = r;
    r.x = fmaxf(acc2.x + bb.x, 0.f); r.y = fmaxf(acc2.y + bb.y, 0.f);
    r.z = fmaxf(acc2.z + bb.z, 0.f); r.w = fmaxf(acc2.w + bb.w, 0.f);
    *(float4*)(o + 2 * Cn) = r;
    r.x = fmaxf(acc3.x + bb.x, 0.f); r.y = fmaxf(acc3.y + bb.y, 0.f);
    r.z = fmaxf(acc3.z + bb.z, 0.f); r.w = fmaxf(acc3.w + bb.w, 0.f);
    *(float4*)(o + 3 * Cn) = r;
}

// ---------------- classifier: out[b0+b] = h[b*N+0] . W_cls + b_cls ----------------
__global__ __launch_bounds__(128) void k_cls(const float* __restrict__ h,
                                             const float* __restrict__ Wcls,
                                             const float* __restrict__ bcls,
                                             float* __restrict__ out) {
    __shared__ float red[128];
    int b = blockIdx.x, t = threadIdx.x;
    red[t] = h[(size_t)b * Nn * Cn + t] * Wcls[t];
    __syncthreads();
    for (int s = 64; s > 0; s >>= 1) {
        if (t < s) red[t] += red[t + s];
        __syncthreads();
    }
    if (t == 0) out[b] = red[0] + bcls[0];
}

extern "C" void kernel_launch(void* const* d_in, const int* in_sizes, int n_in,
                              void* d_out, int out_size, void* d_ws, size_t ws_size,
                              hipStream_t stream) {
    const float* x    = (const float*)d_in[0];
    const int*   ei32 = (const int*)d_in[1];     // int32 per harness spec (int64 auto-detected)
    const float* We   = (const float*)d_in[2];
    const float* be   = (const float*)d_in[3];
    const float* Wc   = (const float*)d_in[4];
    const float* bc   = (const float*)d_in[5];
    const float* Wcls = (const float*)d_in[6];
    const float* bcls = (const float*)d_in[7];
    float* out = (float*)d_out;

    char* ws = (char*)d_ws;
    float* g      = (float*)(ws + 0);
    int*   indeg  = (int*)(ws + 32768);
    int*   meta   = (int*)(ws + 36864);
    int*   offs   = (int*)(ws + 40960);
    int*   cursor = (int*)(ws + 49152);
    int*   ssrc   = (int*)(ws + 53248);

    // chunk size: as many samples as the workspace can double-buffer
    size_t per = (size_t)Nn * Cn * sizeof(float);          // 512 KB per sample
    size_t avail = (ws_size > WS_FIXED) ? (ws_size - WS_FIXED) : 0;
    int G = (int)(avail / (2 * per));
    if (G > Bn) G = Bn;
    if (G < 1) G = 1;
    float* hA = (float*)(ws + WS_FIXED);
    float* hB = hA + (size_t)G * Nn * Cn;

    // CSR build (ws is re-poisoned before every call, so rebuild each time)
    k_zero<<<5, 256, 0, stream>>>(indeg, 1028);            // indeg (1024) + meta (4), contiguous
    k_detect<<<En / 256, 256, 0, stream>>>(ei32, meta);
    k_hist<<<En / 256, 256, 0, stream>>>(ei32, meta, indeg);
    k_scan<<<1, 1024, 0, stream>>>(indeg, offs, cursor);
    k_scatter<<<En / 256, 256, 0, stream>>>(ei32, meta, cursor, ssrc);

    // embedding (row-repeat structure) + g = e @ W_conv, all 64 samples
    k_embed<<<Bn, 512, 0, stream>>>(x, We, be, Wc, g);

    for (int b0 = 0; b0 < Bn; b0 += G) {
        int gc = (Bn - b0 < G) ? (Bn - b0) : G;
        int swz = (gc == 64) ? 1 : 0;
        // conv 1 (identical rows -> broadcast): hA = relu(indeg[n] * g[b] + bc)
        k_h1<<<gc * (Nn * Cn / 4) / 256, 256, 0, stream>>>(g + b0 * Cn, bc, indeg, hA);
        // convs 2..4 (general)
        k_conv<<<gc * 32, 256, 0, stream>>>(hA, hB, Wc, bc, offs, ssrc, swz);
        k_conv<<<gc * 32, 256, 0, stream>>>(hB, hA, Wc, bc, offs, ssrc, swz);
        k_conv<<<gc * 32, 256, 0, stream>>>(hA, hB, Wc, bc, offs, ssrc, swz);
        // classifier on node 0 of each sample in the chunk
        k_cls<<<gc, 128, 0, stream>>>(hB, Wcls, bcls, out + b0);
    }
}

// Round 3
// 246.343 us; speedup vs baseline: 1.8778x; 1.8778x over previous
//
#include <hip/hip_runtime.h>
#include <cstdint>
#include <cstddef>

constexpr int Bn = 64;     // batch
constexpr int Nn = 1024;   // nodes per graph
constexpr int Dn = 1024;   // input feature dim
constexpr int Cn = 128;    // hidden channels
constexpr int En = 16384;  // edges per graph

typedef short s16x8 __attribute__((ext_vector_type(8)));   // 8 bf16 = 4 VGPR (MFMA A/B frag)
typedef float f32x4 __attribute__((ext_vector_type(4)));   // MFMA C/D frag

__device__ __forceinline__ uint32_t f2bf(float f) {        // fp32 -> bf16 bits, RNE
    uint32_t u = __float_as_uint(f);
    return (u + 0x7fffu + ((u >> 16) & 1u)) >> 16;
}
__device__ __forceinline__ float bflo(uint32_t v) { return __uint_as_float(v << 16); }
__device__ __forceinline__ float bfhi(uint32_t v) { return __uint_as_float(v & 0xffff0000u); }

// ---------------- fused CSR build: detect int64/int32, hist, scan, scatter ----------------
// single block, 1024 threads; everything in LDS.
__global__ __launch_bounds__(1024) void k_csr(const int* __restrict__ ei32,
                                              int* __restrict__ indeg,
                                              int* __restrict__ offs,
                                              int* __restrict__ ssrc) {
    __shared__ int sdeg[Nn];
    __shared__ int scur[Nn];
    __shared__ int sflag;
    int t = threadIdx.x;
    sdeg[t] = 0;
    if (t == 0) sflag = 0;
    __syncthreads();
    // int64 detection: node ids < 1024, so int64 layout => all odd 32-bit words are 0
    int f = 0;
    for (int i = t; i < En; i += 1024) f |= ei32[2 * i + 1];
    if (f) atomicOr(&sflag, 1);
    __syncthreads();
    bool i64 = (sflag == 0);
    // histogram of dst
    for (int e = t; e < En; e += 1024) {
        int dst = ei32[i64 ? 2 * (En + e) : (En + e)] & (Nn - 1);
        atomicAdd(&sdeg[dst], 1);
    }
    __syncthreads();
    int v = sdeg[t];
    // inclusive scan (in place)
    for (int off = 1; off < Nn; off <<= 1) {
        int add = (t >= off) ? sdeg[t - off] : 0;
        __syncthreads();
        sdeg[t] += add;
        __syncthreads();
    }
    offs[t + 1] = sdeg[t];
    if (t == 0) offs[0] = 0;
    indeg[t] = v;
    scur[t] = sdeg[t] - v;   // exclusive prefix = write cursor
    __syncthreads();
    // scatter src by dst
    for (int e = t; e < En; e += 1024) {
        int src = ei32[i64 ? 2 * e : e] & (Nn - 1);
        int dst = ei32[i64 ? 2 * (En + e) : (En + e)] & (Nn - 1);
        int pos = atomicAdd(&scur[dst], 1);
        ssrc[pos] = src;
    }
}

// ---------------- W_conv -> bf16, transposed: Wt[n*128 + k] = bf16(Wc[k*128 + n]) ----------------
__global__ void k_wconv(const float* __restrict__ Wc, unsigned short* __restrict__ Wt) {
    int i = blockIdx.x * 256 + threadIdx.x;   // 16384
    int n = i >> 7, k = i & 127;
    Wt[i] = (unsigned short)f2bf(Wc[k * Cn + n]);
}

// ---------------- embedding + g = relu(x_b @ We + be) @ Wc (fp32, exact path) ----------------
// one block per sample; 1024 threads = 8 d-groups x 128 channels
__global__ __launch_bounds__(1024) void k_embed(const float* __restrict__ x,
                                                const float* __restrict__ We,
                                                const float* __restrict__ be,
                                                const float* __restrict__ Wc,
                                                float* __restrict__ g) {
    __shared__ float sx[Dn];
    __shared__ float sp[8 * Cn];
    __shared__ float se[Cn];
    int b = blockIdx.x, tid = threadIdx.x;
    int c = tid & 127, u = tid >> 7;          // u in [0,8)
    sx[tid] = x[b * Dn + tid];
    __syncthreads();
    float acc = 0.f;
    int d0 = u * 128;
#pragma unroll 8
    for (int d = d0; d < d0 + 128; ++d) acc += sx[d] * We[d * Cn + c];
    sp[u * Cn + c] = acc;
    __syncthreads();
    if (u == 0) {
        float e = be[c];
#pragma unroll
        for (int q = 0; q < 8; ++q) e += sp[q * Cn + c];
        se[c] = fmaxf(e, 0.f);
    }
    __syncthreads();
    float ga = 0.f;
    int k0 = u * 16;
#pragma unroll
    for (int k = k0; k < k0 + 16; ++k) ga += se[k] * Wc[k * Cn + c];
    sp[u * Cn + c] = ga;
    __syncthreads();
    if (u == 0) {
        float s = 0.f;
#pragma unroll
        for (int q = 0; q < 8; ++q) s += sp[q * Cn + c];
        g[b * Cn + c] = s;
    }
}

// ---------------- conv #1 (identical rows): h1[b,n,:] = relu(indeg[n]*g[b,:] + bc) -> bf16 ----------------
__global__ void k_h1(const float* __restrict__ g_base, const float* __restrict__ bc,
                     const int* __restrict__ indeg, uint32_t* __restrict__ h) {
    int gid = blockIdx.x * 256 + threadIdx.x;  // over gc*N*64 bf16-pairs
    int c2 = gid & 63;
    int node = gid >> 6;
    int b = node >> 10, n = node & 1023;
    float deg = (float)indeg[n];
    float2 gg = *(const float2*)&g_base[b * Cn + 2 * c2];
    float r0 = fmaxf(deg * gg.x + bc[2 * c2 + 0], 0.f);
    float r1 = fmaxf(deg * gg.y + bc[2 * c2 + 1], 0.f);
    h[(size_t)node * 64 + c2] = f2bf(r0) | (f2bf(r1) << 16);
}

// ---------------- general conv: hn = relu((A h) @ Wc + bc), bf16 in/out, MFMA matmul ----------------
// grid = gc*32 blocks (sample x 32-dst-node tile), 256 threads.
// swz (gc==64): xcd = bidx&7 -> samples [xcd*8,xcd*8+8) stay in one XCD's L2.
constexpr int PAD = 136;     // LDS row stride in bf16 elems (128 + 8: breaks b128 phase conflicts)
constexpr int ECHUNK = 768;  // edge staging chunk
__global__ __launch_bounds__(256, 3) void k_conv(const uint32_t* __restrict__ h,
                                                 unsigned short* __restrict__ hn,
                                                 const unsigned short* __restrict__ Wt,
                                                 const float* __restrict__ bc,
                                                 const int* __restrict__ offs,
                                                 const int* __restrict__ ssrc,
                                                 int swz) {
    __shared__ unsigned short sW[128 * PAD];   // 34816 B : W^T bf16 [n][k]
    __shared__ unsigned short sSb[32 * PAD];   //  8704 B : aggregated tile bf16 [row][k]
    __shared__ int sIdx[ECHUNK];               //  3072 B
    int tid = threadIdx.x;
    int bidx = blockIdx.x;
    int b, dst0;
    if (swz) {
        int xcd = bidx & 7, q = bidx >> 3;
        b = xcd * 8 + (q >> 5);
        dst0 = (q & 31) * 32;
    } else {
        b = bidx >> 5;
        dst0 = (bidx & 31) * 32;
    }

    // ---- stage W^T into LDS (padded rows) ----
    const uint4* Wt4 = (const uint4*)Wt;   // 8 bf16 per uint4; 2048 chunks
    for (int i = tid; i < 2048; i += 256) {
        int flat = i * 8, n = flat >> 7, k = flat & 127;
        *(uint4*)&sW[n * PAD + k] = Wt4[i];
    }

    // ---- aggregation: thread (u in [0,4), c2 in [0,64)) owns rows u*8..u*8+7, channels 2c2,2c2+1 ----
    int c2 = tid & 63, u = tid >> 6;
    const uint32_t* hb = h + (size_t)b * (Nn * 64);
    float aL[8], aH[8];
#pragma unroll
    for (int t0 = 0; t0 < 8; ++t0) { aL[t0] = 0.f; aH[t0] = 0.f; }

    int e_begin = offs[dst0], e_end = offs[dst0 + 32];
    for (int base = e_begin; base < e_end; base += ECHUNK) {
        int cnt = e_end - base; if (cnt > ECHUNK) cnt = ECHUNK;
        __syncthreads();
        for (int i = tid; i < cnt; i += 256) sIdx[i] = ssrc[base + i];
        __syncthreads();
#pragma unroll
        for (int t0 = 0; t0 < 8; ++t0) {
            int dst = dst0 + u * 8 + t0;
            int lo = offs[dst], hi = offs[dst + 1];
            int j0 = (lo > base ? lo : base) - base;
            int j1 = ((hi < base + cnt) ? hi : base + cnt) - base;
            float s0 = aL[t0], s1 = aH[t0];
            int j = j0;
            for (; j + 8 <= j1; j += 8) {
                int i0 = sIdx[j], i1 = sIdx[j + 1], i2 = sIdx[j + 2], i3 = sIdx[j + 3];
                int i4 = sIdx[j + 4], i5 = sIdx[j + 5], i6 = sIdx[j + 6], i7 = sIdx[j + 7];
                uint32_t v0 = hb[i0 * 64 + c2], v1 = hb[i1 * 64 + c2];
                uint32_t v2 = hb[i2 * 64 + c2], v3 = hb[i3 * 64 + c2];
                uint32_t v4 = hb[i4 * 64 + c2], v5 = hb[i5 * 64 + c2];
                uint32_t v6 = hb[i6 * 64 + c2], v7 = hb[i7 * 64 + c2];
                s0 += (bflo(v0) + bflo(v1)) + (bflo(v2) + bflo(v3)) +
                      (bflo(v4) + bflo(v5)) + (bflo(v6) + bflo(v7));
                s1 += (bfhi(v0) + bfhi(v1)) + (bfhi(v2) + bfhi(v3)) +
                      (bfhi(v4) + bfhi(v5)) + (bfhi(v6) + bfhi(v7));
            }
            for (; j < j1; ++j) {
                uint32_t v = hb[sIdx[j] * 64 + c2];
                s0 += bflo(v); s1 += bfhi(v);
            }
            aL[t0] = s0; aH[t0] = s1;
        }
    }
    // write aggregated tile as bf16 into sSb
#pragma unroll
    for (int t0 = 0; t0 < 8; ++t0) {
        int row = u * 8 + t0;
        uint32_t pk = f2bf(aL[t0]) | (f2bf(aH[t0]) << 16);
        *(uint32_t*)&sSb[row * PAD + 2 * c2] = pk;
    }
    __syncthreads();

    // ---- MFMA: 32x128 = (32x128 agg) @ (128x128 W), 16x16x32 bf16 ----
    // wave w covers cols [w*32, w*32+32); 2 row-tiles x 2 col-tiles x 4 k-steps
    int lane = tid & 63, w = tid >> 6;
    int m = lane & 15, quad = lane >> 4;
    f32x4 acc[2][2];
#pragma unroll
    for (int rt = 0; rt < 2; ++rt)
#pragma unroll
        for (int ct = 0; ct < 2; ++ct) acc[rt][ct] = (f32x4){0.f, 0.f, 0.f, 0.f};

#pragma unroll
    for (int ks = 0; ks < 4; ++ks) {
        int ko = ks * 32 + quad * 8;
        s16x8 a0 = *(const s16x8*)&sSb[(0 * 16 + m) * PAD + ko];
        s16x8 a1 = *(const s16x8*)&sSb[(1 * 16 + m) * PAD + ko];
        s16x8 b0 = *(const s16x8*)&sW[(w * 32 + 0 * 16 + m) * PAD + ko];
        s16x8 b1 = *(const s16x8*)&sW[(w * 32 + 1 * 16 + m) * PAD + ko];
        acc[0][0] = __builtin_amdgcn_mfma_f32_16x16x32_bf16(a0, b0, acc[0][0], 0, 0, 0);
        acc[0][1] = __builtin_amdgcn_mfma_f32_16x16x32_bf16(a0, b1, acc[0][1], 0, 0, 0);
        acc[1][0] = __builtin_amdgcn_mfma_f32_16x16x32_bf16(a1, b0, acc[1][0], 0, 0, 0);
        acc[1][1] = __builtin_amdgcn_mfma_f32_16x16x32_bf16(a1, b1, acc[1][1], 0, 0, 0);
    }

    // epilogue: +bias, relu, bf16 store. C/D: col = lane&15, row = quad*4 + reg
    unsigned short* ob = hn + ((size_t)b * Nn + dst0) * Cn;
#pragma unroll
    for (int rt = 0; rt < 2; ++rt)
#pragma unroll
        for (int ct = 0; ct < 2; ++ct) {
            int col = w * 32 + ct * 16 + m;
            float bias = bc[col];
#pragma unroll
            for (int reg = 0; reg < 4; ++reg) {
                int row = rt * 16 + quad * 4 + reg;
                float val = fmaxf(acc[rt][ct][reg] + bias, 0.f);
                ob[row * Cn + col] = (unsigned short)f2bf(val);
            }
        }
}

// ---------------- classifier: out[b] = h_bf16[b*N + 0] . W_cls + b_cls ----------------
__global__ __launch_bounds__(128) void k_cls(const unsigned short* __restrict__ h,
                                             const float* __restrict__ Wcls,
                                             const float* __restrict__ bcls,
                                             float* __restrict__ out) {
    __shared__ float red[128];
    int b = blockIdx.x, t = threadIdx.x;
    float hv = __uint_as_float(((uint32_t)h[(size_t)b * Nn * Cn + t]) << 16);
    red[t] = hv * Wcls[t];
    __syncthreads();
    for (int s = 64; s > 0; s >>= 1) {
        if (t < s) red[t] += red[t + s];
        __syncthreads();
    }
    if (t == 0) out[b] = red[0] + bcls[0];
}

extern "C" void kernel_launch(void* const* d_in, const int* in_sizes, int n_in,
                              void* d_out, int out_size, void* d_ws, size_t ws_size,
                              hipStream_t stream) {
    const float* x    = (const float*)d_in[0];
    const int*   ei32 = (const int*)d_in[1];
    const float* We   = (const float*)d_in[2];
    const float* be   = (const float*)d_in[3];
    const float* Wc   = (const float*)d_in[4];
    const float* bc   = (const float*)d_in[5];
    const float* Wcls = (const float*)d_in[6];
    const float* bcls = (const float*)d_in[7];
    float* out = (float*)d_out;

    // ---- workspace layout ----
    // 0       g      32768   (B x C fp32)
    // 32768   indeg   4096
    // 36864   offs    8192   (needs 4100)
    // 45056   ssrc   65536
    // 110592  Wt     32768   (128x128 bf16, transposed)
    // 143360  heap: ping-pong bf16 h buffers, G*N*C*2 B each
    constexpr size_t WS_FIXED = 143360;
    char* ws = (char*)d_ws;
    float*          g     = (float*)(ws + 0);
    int*            indeg = (int*)(ws + 32768);
    int*            offs  = (int*)(ws + 36864);
    int*            ssrc  = (int*)(ws + 45056);
    unsigned short* Wt    = (unsigned short*)(ws + 110592);

    size_t per = (size_t)Nn * Cn * 2;     // 256 KB per sample (bf16)
    size_t avail = (ws_size > WS_FIXED) ? (ws_size - WS_FIXED) : 0;
    int G = (int)(avail / (2 * per));
    if (G > Bn) G = Bn;
    if (G < 1) G = 1;
    unsigned short* hA = (unsigned short*)(ws + WS_FIXED);
    unsigned short* hB = hA + (size_t)G * Nn * Cn;

    k_csr<<<1, 1024, 0, stream>>>(ei32, indeg, offs, ssrc);
    k_wconv<<<64, 256, 0, stream>>>(Wc, Wt);
    k_embed<<<Bn, 1024, 0, stream>>>(x, We, be, Wc, g);

    for (int b0 = 0; b0 < Bn; b0 += G) {
        int gc = (Bn - b0 < G) ? (Bn - b0) : G;
        int swz = (gc == 64) ? 1 : 0;
        k_h1<<<gc * 256, 256, 0, stream>>>(g + b0 * Cn, bc, indeg, (uint32_t*)hA);
        k_conv<<<gc * 32, 256, 0, stream>>>((const uint32_t*)hA, hB, Wt, bc, offs, ssrc, swz);
        k_conv<<<gc * 32, 256, 0, stream>>>((const uint32_t*)hB, hA, Wt, bc, offs, ssrc, swz);
        k_conv<<<gc * 32, 256, 0, stream>>>((const uint32_t*)hA, hB, Wt, bc, offs, ssrc, swz);
        k_cls<<<gc, 128, 0, stream>>>(hB, Wcls, bcls, out + b0);
    }
}

// Round 4
// 218.188 us; speedup vs baseline: 2.1201x; 1.1290x over previous
//
#include <hip/hip_runtime.h>
#include <cstdint>
#include <cstddef>

constexpr int Bn = 64;     // batch
constexpr int Nn = 1024;   // nodes per graph
constexpr int Dn = 1024;   // input feature dim
constexpr int Cn = 128;    // hidden channels
constexpr int En = 16384;  // edges per graph

typedef short s16x8 __attribute__((ext_vector_type(8)));   // 8 bf16 = 4 VGPR (MFMA A/B frag)
typedef float f32x4 __attribute__((ext_vector_type(4)));   // MFMA C/D frag

__device__ __forceinline__ uint32_t f2bf(float f) {        // fp32 -> bf16 bits, RNE
    uint32_t u = __float_as_uint(f);
    return (u + 0x7fffu + ((u >> 16) & 1u)) >> 16;
}
__device__ __forceinline__ float bflo(uint32_t v) { return __uint_as_float(v << 16); }
__device__ __forceinline__ float bfhi(uint32_t v) { return __uint_as_float(v & 0xffff0000u); }

// ---------------- CSR build (parallel) ----------------
__global__ void k_zero(int* __restrict__ p, int n) {
    int i = blockIdx.x * 256 + threadIdx.x;
    if (i < n) p[i] = 0;
}

// int64 detection: node ids < 1024 => int64 layout has all odd 32-bit words zero
__global__ void k_detect(const int* __restrict__ ei32, int* __restrict__ meta) {
    __shared__ int sh;
    if (threadIdx.x == 0) sh = 0;
    __syncthreads();
    int i = blockIdx.x * 256 + threadIdx.x;   // [0, 2*En/2)
    if (ei32[2 * i + 1]) atomicOr(&sh, 1);
    __syncthreads();
    if (threadIdx.x == 0 && sh) atomicOr(meta, 1);   // meta!=0 => genuine int32
}

__global__ void k_hist(const int* __restrict__ ei32, const int* __restrict__ meta,
                       int* __restrict__ indeg) {
    int e = blockIdx.x * 256 + threadIdx.x;
    bool i64 = (meta[0] == 0);
    int dst = ei32[i64 ? 2 * (En + e) : (En + e)] & (Nn - 1);
    atomicAdd(&indeg[dst], 1);
}

__global__ __launch_bounds__(1024) void k_scan(const int* __restrict__ indeg,
                                               int* __restrict__ offs,
                                               int* __restrict__ cursor) {
    __shared__ int tmp[Nn];
    int t = threadIdx.x;
    int v = indeg[t];
    tmp[t] = v;
    __syncthreads();
    for (int off = 1; off < Nn; off <<= 1) {
        int add = (t >= off) ? tmp[t - off] : 0;
        __syncthreads();
        tmp[t] += add;
        __syncthreads();
    }
    offs[t + 1] = tmp[t];
    if (t == 0) offs[0] = 0;
    cursor[t] = tmp[t] - v;   // exclusive prefix
}

__global__ void k_scatter(const int* __restrict__ ei32, const int* __restrict__ meta,
                          int* __restrict__ cursor, int* __restrict__ ssrc) {
    int e = blockIdx.x * 256 + threadIdx.x;
    bool i64 = (meta[0] == 0);
    int src = ei32[i64 ? 2 * e : e] & (Nn - 1);
    int dst = ei32[i64 ? 2 * (En + e) : (En + e)] & (Nn - 1);
    int pos = atomicAdd(&cursor[dst], 1);
    if (pos >= 0 && pos < En) ssrc[pos] = src;
}

// ---------------- W_conv -> bf16, transposed: Wt[n*128 + k] = bf16(Wc[k*128 + n]) ----------------
__global__ void k_wconv(const float* __restrict__ Wc, unsigned short* __restrict__ Wt) {
    int i = blockIdx.x * 256 + threadIdx.x;   // 16384
    int n = i >> 7, k = i & 127;
    Wt[i] = (unsigned short)f2bf(Wc[k * Cn + n]);
}

// ---------------- embedding stage A: partial dots ----------------
// 256 blocks: (b = bid>>2, q = bid&3); 256 threads = (c = tid&127, h2 = tid>>7)
__global__ __launch_bounds__(256) void k_embedA(const float* __restrict__ x,
                                                const float* __restrict__ We,
                                                float* __restrict__ pws) {
    __shared__ float sx[256];
    __shared__ float sp[256];
    int bid = blockIdx.x, tid = threadIdx.x;
    int b = bid >> 2, q = bid & 3;
    int c = tid & 127, h2 = tid >> 7;
    sx[tid] = x[b * Dn + q * 256 + tid];
    __syncthreads();
    float acc = 0.f;
    int d0 = q * 256 + h2 * 128;
    int dl = h2 * 128;
#pragma unroll 8
    for (int i = 0; i < 128; ++i) acc += sx[dl + i] * We[(d0 + i) * Cn + c];
    sp[h2 * 128 + c] = acc;
    __syncthreads();
    if (h2 == 0) pws[(b * 4 + q) * Cn + c] = sp[c] + sp[128 + c];
}

// ---------------- embedding stage B: e = relu(sum partials + be); g = e @ Wc ----------------
__global__ __launch_bounds__(128) void k_g(const float* __restrict__ pws,
                                           const float* __restrict__ be,
                                           const float* __restrict__ Wc,
                                           float* __restrict__ g) {
    __shared__ float se[Cn];
    int b = blockIdx.x, c = threadIdx.x;
    float e = pws[(b * 4 + 0) * Cn + c] + pws[(b * 4 + 1) * Cn + c] +
              pws[(b * 4 + 2) * Cn + c] + pws[(b * 4 + 3) * Cn + c] + be[c];
    se[c] = fmaxf(e, 0.f);
    __syncthreads();
    float ga = 0.f;
#pragma unroll 8
    for (int k = 0; k < Cn; ++k) ga += se[k] * Wc[k * Cn + c];
    g[b * Cn + c] = ga;
}

// ---------------- conv #1 (identical rows): h1[b,n,:] = relu(indeg[n]*g[b,:] + bc) -> bf16 ----------------
__global__ void k_h1(const float* __restrict__ g_base, const float* __restrict__ bc,
                     const int* __restrict__ indeg, uint32_t* __restrict__ h) {
    int gid = blockIdx.x * 256 + threadIdx.x;  // over gc*N*64 bf16-pairs
    int c2 = gid & 63;
    int node = gid >> 6;
    int b = node >> 10, n = node & 1023;
    float deg = (float)indeg[n];
    float2 gg = *(const float2*)&g_base[b * Cn + 2 * c2];
    float r0 = fmaxf(deg * gg.x + bc[2 * c2 + 0], 0.f);
    float r1 = fmaxf(deg * gg.y + bc[2 * c2 + 1], 0.f);
    h[(size_t)node * 64 + c2] = f2bf(r0) | (f2bf(r1) << 16);
}

// ---------------- general conv: hn = relu((A h) @ Wc + bc), bf16, MFMA ----------------
// grid = gc*32 blocks (sample x 32-dst-node tile), 256 threads.
// LDS = 11.8 KB only (W^T fragments live in registers, loaded from global Wt which is L2-hot).
constexpr int PAD = 136;     // LDS row stride in bf16 elems
constexpr int ECHUNK = 768;  // edge staging chunk
__global__ __launch_bounds__(256, 4) void k_conv(const uint32_t* __restrict__ h,
                                                 unsigned short* __restrict__ hn,
                                                 const unsigned short* __restrict__ Wt,
                                                 const float* __restrict__ bc,
                                                 const int* __restrict__ offs,
                                                 const int* __restrict__ ssrc,
                                                 int swz) {
    __shared__ unsigned short sSb[32 * PAD];   // 8704 B : aggregated tile bf16 [row][k]
    __shared__ int sIdx[ECHUNK];               // 3072 B
    int tid = threadIdx.x;
    int bidx = blockIdx.x;
    int b, dst0;
    if (swz) {
        int xcd = bidx & 7, q = bidx >> 3;
        b = xcd * 8 + (q >> 5);
        dst0 = (q & 31) * 32;
    } else {
        b = bidx >> 5;
        dst0 = (bidx & 31) * 32;
    }

    // ---- aggregation: thread (u in [0,4), c2 in [0,64)) owns rows u*8..u*8+7, channels 2c2,2c2+1 ----
    int c2 = tid & 63, u = tid >> 6;
    const uint32_t* hb = h + (size_t)b * (Nn * 64);
    float aL[8], aH[8];
#pragma unroll
    for (int t0 = 0; t0 < 8; ++t0) { aL[t0] = 0.f; aH[t0] = 0.f; }

    int e_begin = offs[dst0], e_end = offs[dst0 + 32];
    for (int base = e_begin; base < e_end; base += ECHUNK) {
        int cnt = e_end - base; if (cnt > ECHUNK) cnt = ECHUNK;
        __syncthreads();
        for (int i = tid; i < cnt; i += 256) sIdx[i] = ssrc[base + i];
        __syncthreads();
#pragma unroll
        for (int t0 = 0; t0 < 8; ++t0) {
            int dst = dst0 + u * 8 + t0;
            int lo = offs[dst], hi = offs[dst + 1];
            int j0 = (lo > base ? lo : base) - base;
            int j1 = ((hi < base + cnt) ? hi : base + cnt) - base;
            float s0 = aL[t0], s1 = aH[t0];
            int j = j0;
            for (; j + 8 <= j1; j += 8) {
                int i0 = sIdx[j], i1 = sIdx[j + 1], i2 = sIdx[j + 2], i3 = sIdx[j + 3];
                int i4 = sIdx[j + 4], i5 = sIdx[j + 5], i6 = sIdx[j + 6], i7 = sIdx[j + 7];
                uint32_t v0 = hb[i0 * 64 + c2], v1 = hb[i1 * 64 + c2];
                uint32_t v2 = hb[i2 * 64 + c2], v3 = hb[i3 * 64 + c2];
                uint32_t v4 = hb[i4 * 64 + c2], v5 = hb[i5 * 64 + c2];
                uint32_t v6 = hb[i6 * 64 + c2], v7 = hb[i7 * 64 + c2];
                s0 += (bflo(v0) + bflo(v1)) + (bflo(v2) + bflo(v3)) +
                      (bflo(v4) + bflo(v5)) + (bflo(v6) + bflo(v7));
                s1 += (bfhi(v0) + bfhi(v1)) + (bfhi(v2) + bfhi(v3)) +
                      (bfhi(v4) + bfhi(v5)) + (bfhi(v6) + bfhi(v7));
            }
            for (; j < j1; ++j) {
                uint32_t v = hb[sIdx[j] * 64 + c2];
                s0 += bflo(v); s1 += bfhi(v);
            }
            aL[t0] = s0; aH[t0] = s1;
        }
    }
    // write aggregated tile as bf16 into sSb
#pragma unroll
    for (int t0 = 0; t0 < 8; ++t0) {
        int row = u * 8 + t0;
        uint32_t pk = f2bf(aL[t0]) | (f2bf(aH[t0]) << 16);
        *(uint32_t*)&sSb[row * PAD + 2 * c2] = pk;
    }

    // ---- B-fragments straight from global (Wt is 32 KB, L2/L1-hot) ----
    int lane = tid & 63, w = tid >> 6;
    int m = lane & 15, quad = lane >> 4;
    s16x8 bf0[4], bf1[4];
#pragma unroll
    for (int ks = 0; ks < 4; ++ks) {
        int ko = ks * 32 + quad * 8;
        bf0[ks] = *(const s16x8*)&Wt[(w * 32 + m) * Cn + ko];
        bf1[ks] = *(const s16x8*)&Wt[(w * 32 + 16 + m) * Cn + ko];
    }
    __syncthreads();

    // ---- MFMA: (32x128 agg) @ (128x128 W) via 16x16x32 bf16 ----
    f32x4 acc[2][2];
#pragma unroll
    for (int rt = 0; rt < 2; ++rt)
#pragma unroll
        for (int ct = 0; ct < 2; ++ct) acc[rt][ct] = (f32x4){0.f, 0.f, 0.f, 0.f};

#pragma unroll
    for (int ks = 0; ks < 4; ++ks) {
        int ko = ks * 32 + quad * 8;
        s16x8 a0 = *(const s16x8*)&sSb[(0 * 16 + m) * PAD + ko];
        s16x8 a1 = *(const s16x8*)&sSb[(1 * 16 + m) * PAD + ko];
        acc[0][0] = __builtin_amdgcn_mfma_f32_16x16x32_bf16(a0, bf0[ks], acc[0][0], 0, 0, 0);
        acc[0][1] = __builtin_amdgcn_mfma_f32_16x16x32_bf16(a0, bf1[ks], acc[0][1], 0, 0, 0);
        acc[1][0] = __builtin_amdgcn_mfma_f32_16x16x32_bf16(a1, bf0[ks], acc[1][0], 0, 0, 0);
        acc[1][1] = __builtin_amdgcn_mfma_f32_16x16x32_bf16(a1, bf1[ks], acc[1][1], 0, 0, 0);
    }

    // epilogue: +bias, relu, bf16 store. C/D: col = lane&15, row = quad*4 + reg
    unsigned short* ob = hn + ((size_t)b * Nn + dst0) * Cn;
#pragma unroll
    for (int rt = 0; rt < 2; ++rt)
#pragma unroll
        for (int ct = 0; ct < 2; ++ct) {
            int col = w * 32 + ct * 16 + m;
            float bias = bc[col];
#pragma unroll
            for (int reg = 0; reg < 4; ++reg) {
                int row = rt * 16 + quad * 4 + reg;
                float val = fmaxf(acc[rt][ct][reg] + bias, 0.f);
                ob[row * Cn + col] = (unsigned short)f2bf(val);
            }
        }
}

// ---------------- classifier: out[b] = h_bf16[b*N + 0] . W_cls + b_cls ----------------
__global__ __launch_bounds__(128) void k_cls(const unsigned short* __restrict__ h,
                                             const float* __restrict__ Wcls,
                                             const float* __restrict__ bcls,
                                             float* __restrict__ out) {
    __shared__ float red[128];
    int b = blockIdx.x, t = threadIdx.x;
    float hv = __uint_as_float(((uint32_t)h[(size_t)b * Nn * Cn + t]) << 16);
    red[t] = hv * Wcls[t];
    __syncthreads();
    for (int s = 64; s > 0; s >>= 1) {
        if (t < s) red[t] += red[t + s];
        __syncthreads();
    }
    if (t == 0) out[b] = red[0] + bcls[0];
}

extern "C" void kernel_launch(void* const* d_in, const int* in_sizes, int n_in,
                              void* d_out, int out_size, void* d_ws, size_t ws_size,
                              hipStream_t stream) {
    const float* x    = (const float*)d_in[0];
    const int*   ei32 = (const int*)d_in[1];
    const float* We   = (const float*)d_in[2];
    const float* be   = (const float*)d_in[3];
    const float* Wc   = (const float*)d_in[4];
    const float* bc   = (const float*)d_in[5];
    const float* Wcls = (const float*)d_in[6];
    const float* bcls = (const float*)d_in[7];
    float* out = (float*)d_out;

    // ---- workspace layout ----
    // 0       g      32768   (B x C fp32)
    // 32768   indeg   4096
    // 36864   meta    4096   (meta[0] = int32-detection flag)
    // 40960   offs    8192
    // 49152   cursor  4096
    // 53248   ssrc   65536
    // 118784  Wt     32768   (128x128 bf16, transposed)
    // 151552  pws   131072   (embed partials: B*4 x C fp32)
    // 282624  heap: ping-pong bf16 h buffers
    constexpr size_t WS_FIXED = 282624;
    char* ws = (char*)d_ws;
    float*          g      = (float*)(ws + 0);
    int*            indeg  = (int*)(ws + 32768);
    int*            meta   = (int*)(ws + 36864);
    int*            offs   = (int*)(ws + 40960);
    int*            cursor = (int*)(ws + 49152);
    int*            ssrc   = (int*)(ws + 53248);
    unsigned short* Wt     = (unsigned short*)(ws + 118784);
    float*          pws    = (float*)(ws + 151552);

    size_t per = (size_t)Nn * Cn * 2;     // 256 KB per sample (bf16)
    size_t avail = (ws_size > WS_FIXED) ? (ws_size - WS_FIXED) : 0;
    int G = (int)(avail / (2 * per));
    if (G > Bn) G = Bn;
    if (G < 1) G = 1;
    unsigned short* hA = (unsigned short*)(ws + WS_FIXED);
    unsigned short* hB = hA + (size_t)G * Nn * Cn;

    // CSR build (parallel; ws re-poisoned every call so rebuild)
    k_zero<<<8, 256, 0, stream>>>(indeg, 2048);           // indeg + meta contiguous
    k_detect<<<64, 256, 0, stream>>>(ei32, meta);
    k_hist<<<64, 256, 0, stream>>>(ei32, meta, indeg);
    k_scan<<<1, 1024, 0, stream>>>(indeg, offs, cursor);
    k_scatter<<<64, 256, 0, stream>>>(ei32, meta, cursor, ssrc);

    k_wconv<<<64, 256, 0, stream>>>(Wc, Wt);
    k_embedA<<<256, 256, 0, stream>>>(x, We, pws);
    k_g<<<64, 128, 0, stream>>>(pws, be, Wc, g);

    for (int b0 = 0; b0 < Bn; b0 += G) {
        int gc = (Bn - b0 < G) ? (Bn - b0) : G;
        int swz = (gc == 64) ? 1 : 0;
        k_h1<<<gc * 256, 256, 0, stream>>>(g + b0 * Cn, bc, indeg, (uint32_t*)hA);
        k_conv<<<gc * 32, 256, 0, stream>>>((const uint32_t*)hA, hB, Wt, bc, offs, ssrc, swz);
        k_conv<<<gc * 32, 256, 0, stream>>>((const uint32_t*)hB, hA, Wt, bc, offs, ssrc, swz);
        k_conv<<<gc * 32, 256, 0, stream>>>((const uint32_t*)hA, hB, Wt, bc, offs, ssrc, swz);
        k_cls<<<gc, 128, 0, stream>>>(hB, Wcls, bcls, out + b0);
    }
}

// Round 5
// 184.450 us; speedup vs baseline: 2.5079x; 1.1829x over previous
//
#include <hip/hip_runtime.h>
#include <cstdint>
#include <cstddef>

constexpr int Bn = 64;     // batch
constexpr int Nn = 1024;   // nodes per graph
constexpr int Dn = 1024;   // input feature dim
constexpr int Cn = 128;    // hidden channels
constexpr int En = 16384;  // edges per graph

typedef short s16x8 __attribute__((ext_vector_type(8)));   // 8 bf16 = 4 VGPR (MFMA A/B frag)
typedef float f32x4 __attribute__((ext_vector_type(4)));   // MFMA C/D frag

__device__ __forceinline__ uint32_t f2bf(float f) {        // fp32 -> bf16 bits, RNE
    uint32_t u = __float_as_uint(f);
    return (u + 0x7fffu + ((u >> 16) & 1u)) >> 16;
}
__device__ __forceinline__ float bflo(uint32_t v) { return __uint_as_float(v << 16); }
__device__ __forceinline__ float bfhi(uint32_t v) { return __uint_as_float(v & 0xffff0000u); }

// ---------------- prep: zero indeg | int64-detect | Wc -> bf16 transposed ----------------
// blocks 0..3: zero indeg; 4..67: detect; 68..131: wconv.
// meta[1] protocol: ws is poisoned 0xAA, so meta[1]==1 only if a detect block wrote it
// (all writers store the same value 1 -> benign race). int64 data (ids<1024) has all odd
// 32-bit words zero -> meta[1] stays poisoned -> treated as int64.
__global__ __launch_bounds__(256) void k_prep(const int* __restrict__ ei32,
                                              const float* __restrict__ Wc,
                                              int* __restrict__ indeg,
                                              int* __restrict__ meta,
                                              unsigned short* __restrict__ Wt) {
    int bid = blockIdx.x, tid = threadIdx.x;
    if (bid < 4) {
        indeg[bid * 256 + tid] = 0;
    } else if (bid < 68) {
        __shared__ int sh;
        if (tid == 0) sh = 0;
        __syncthreads();
        int i = (bid - 4) * 256 + tid;          // [0, 16384)
        if (ei32[2 * i + 1]) atomicOr(&sh, 1);
        __syncthreads();
        if (tid == 0 && sh) meta[1] = 1;        // same value from all writers
    } else {
        int i = (bid - 68) * 256 + tid;         // [0, 16384)
        int n = i >> 7, k = i & 127;
        Wt[i] = (unsigned short)f2bf(Wc[k * Cn + n]);
    }
}

__global__ void k_hist(const int* __restrict__ ei32, const int* __restrict__ meta,
                       int* __restrict__ indeg) {
    int e = blockIdx.x * 256 + threadIdx.x;
    bool i64 = (meta[1] != 1);
    int dst = ei32[i64 ? 2 * (En + e) : (En + e)] & (Nn - 1);
    atomicAdd(&indeg[dst], 1);
}

__global__ __launch_bounds__(1024) void k_scan(const int* __restrict__ indeg,
                                               int* __restrict__ offs,
                                               int* __restrict__ cursor) {
    __shared__ int tmp[Nn];
    int t = threadIdx.x;
    int v = indeg[t];
    tmp[t] = v;
    __syncthreads();
    for (int off = 1; off < Nn; off <<= 1) {
        int add = (t >= off) ? tmp[t - off] : 0;
        __syncthreads();
        tmp[t] += add;
        __syncthreads();
    }
    offs[t + 1] = tmp[t];
    if (t == 0) offs[0] = 0;
    cursor[t] = tmp[t] - v;   // exclusive prefix
}

__global__ void k_scatter(const int* __restrict__ ei32, const int* __restrict__ meta,
                          int* __restrict__ cursor, int* __restrict__ ssrc) {
    int e = blockIdx.x * 256 + threadIdx.x;
    bool i64 = (meta[1] != 1);
    int src = ei32[i64 ? 2 * e : e] & (Nn - 1);
    int dst = ei32[i64 ? 2 * (En + e) : (En + e)] & (Nn - 1);
    int pos = atomicAdd(&cursor[dst], 1);
    if (pos >= 0 && pos < En) ssrc[pos] = src;
}

// ---------------- embedding stage A: partial dots ----------------
__global__ __launch_bounds__(256) void k_embedA(const float* __restrict__ x,
                                                const float* __restrict__ We,
                                                float* __restrict__ pws) {
    __shared__ float sx[256];
    __shared__ float sp[256];
    int bid = blockIdx.x, tid = threadIdx.x;
    int b = bid >> 2, q = bid & 3;
    int c = tid & 127, h2 = tid >> 7;
    sx[tid] = x[b * Dn + q * 256 + tid];
    __syncthreads();
    float acc = 0.f;
    int d0 = q * 256 + h2 * 128;
    int dl = h2 * 128;
#pragma unroll 8
    for (int i = 0; i < 128; ++i) acc += sx[dl + i] * We[(d0 + i) * Cn + c];
    sp[h2 * 128 + c] = acc;
    __syncthreads();
    if (h2 == 0) pws[(b * 4 + q) * Cn + c] = sp[c] + sp[128 + c];
}

// ---------------- embedding stage B: e = relu(sum partials + be); g = e @ Wc ----------------
__global__ __launch_bounds__(128) void k_g(const float* __restrict__ pws,
                                           const float* __restrict__ be,
                                           const float* __restrict__ Wc,
                                           float* __restrict__ g) {
    __shared__ float se[Cn];
    int b = blockIdx.x, c = threadIdx.x;
    float e = pws[(b * 4 + 0) * Cn + c] + pws[(b * 4 + 1) * Cn + c] +
              pws[(b * 4 + 2) * Cn + c] + pws[(b * 4 + 3) * Cn + c] + be[c];
    se[c] = fmaxf(e, 0.f);
    __syncthreads();
    float ga = 0.f;
#pragma unroll 8
    for (int k = 0; k < Cn; ++k) ga += se[k] * Wc[k * Cn + c];
    g[b * Cn + c] = ga;
}

constexpr int PAD = 136;     // LDS row stride in bf16 elems
constexpr int ECHUNK = 768;  // edge staging chunk

// ---------------- conv 1+2 fused: agg[dst,c] = sum_src relu(indeg[src]*g[b,c]+bc[c]);
//                  hn = relu(agg @ Wc + bc). No global gather: all inputs LDS/register. ----------------
__global__ __launch_bounds__(256, 4) void k_conv2f(const float* __restrict__ g,
                                                   unsigned short* __restrict__ hn,
                                                   const unsigned short* __restrict__ Wt,
                                                   const float* __restrict__ bc,
                                                   const int* __restrict__ indeg,
                                                   const int* __restrict__ offs,
                                                   const int* __restrict__ ssrc,
                                                   int swz) {
    __shared__ float sdeg[Nn];                 // 4 KB
    __shared__ unsigned short sSb[32 * PAD];   // 8.7 KB
    __shared__ int sIdx[ECHUNK];               // 3 KB
    int tid = threadIdx.x, bidx = blockIdx.x;
    int b, dst0;
    if (swz) {
        int xcd = bidx & 7, q = bidx >> 3;
        b = xcd * 8 + (q >> 5);
        dst0 = (q & 31) * 32;
    } else {
        b = bidx >> 5;
        dst0 = (bidx & 31) * 32;
    }
    for (int i = tid; i < Nn; i += 256) sdeg[i] = (float)indeg[i];

    int c2 = tid & 63, u = tid >> 6;
    float gx = g[b * Cn + 2 * c2], gy = g[b * Cn + 2 * c2 + 1];
    float bx = bc[2 * c2], by = bc[2 * c2 + 1];
    float aL[8], aH[8];
#pragma unroll
    for (int t0 = 0; t0 < 8; ++t0) { aL[t0] = 0.f; aH[t0] = 0.f; }

    int e_begin = offs[dst0], e_end = offs[dst0 + 32];
    for (int base = e_begin; base < e_end; base += ECHUNK) {
        int cnt = e_end - base; if (cnt > ECHUNK) cnt = ECHUNK;
        __syncthreads();
        for (int i = tid; i < cnt; i += 256) sIdx[i] = ssrc[base + i];
        __syncthreads();
#pragma unroll
        for (int t0 = 0; t0 < 8; ++t0) {
            int dst = dst0 + u * 8 + t0;
            int lo = offs[dst], hi = offs[dst + 1];
            int j0 = (lo > base ? lo : base) - base;
            int j1 = ((hi < base + cnt) ? hi : base + cnt) - base;
            float s0 = aL[t0], s1 = aH[t0];
            for (int j = j0; j < j1; ++j) {
                float d = sdeg[sIdx[j]];
                s0 += fmaxf(fmaf(d, gx, bx), 0.f);
                s1 += fmaxf(fmaf(d, gy, by), 0.f);
            }
            aL[t0] = s0; aH[t0] = s1;
        }
    }
#pragma unroll
    for (int t0 = 0; t0 < 8; ++t0) {
        int row = u * 8 + t0;
        *(uint32_t*)&sSb[row * PAD + 2 * c2] = f2bf(aL[t0]) | (f2bf(aH[t0]) << 16);
    }

    // B-fragments from global Wt (32 KB, L2-hot)
    int lane = tid & 63, w = tid >> 6;
    int m = lane & 15, quad = lane >> 4;
    s16x8 bf0[4], bf1[4];
#pragma unroll
    for (int ks = 0; ks < 4; ++ks) {
        int ko = ks * 32 + quad * 8;
        bf0[ks] = *(const s16x8*)&Wt[(w * 32 + m) * Cn + ko];
        bf1[ks] = *(const s16x8*)&Wt[(w * 32 + 16 + m) * Cn + ko];
    }
    __syncthreads();

    f32x4 acc[2][2];
#pragma unroll
    for (int rt = 0; rt < 2; ++rt)
#pragma unroll
        for (int ct = 0; ct < 2; ++ct) acc[rt][ct] = (f32x4){0.f, 0.f, 0.f, 0.f};
#pragma unroll
    for (int ks = 0; ks < 4; ++ks) {
        int ko = ks * 32 + quad * 8;
        s16x8 a0 = *(const s16x8*)&sSb[(0 * 16 + m) * PAD + ko];
        s16x8 a1 = *(const s16x8*)&sSb[(1 * 16 + m) * PAD + ko];
        acc[0][0] = __builtin_amdgcn_mfma_f32_16x16x32_bf16(a0, bf0[ks], acc[0][0], 0, 0, 0);
        acc[0][1] = __builtin_amdgcn_mfma_f32_16x16x32_bf16(a0, bf1[ks], acc[0][1], 0, 0, 0);
        acc[1][0] = __builtin_amdgcn_mfma_f32_16x16x32_bf16(a1, bf0[ks], acc[1][0], 0, 0, 0);
        acc[1][1] = __builtin_amdgcn_mfma_f32_16x16x32_bf16(a1, bf1[ks], acc[1][1], 0, 0, 0);
    }

    unsigned short* ob = hn + ((size_t)b * Nn + dst0) * Cn;
#pragma unroll
    for (int rt = 0; rt < 2; ++rt)
#pragma unroll
        for (int ct = 0; ct < 2; ++ct) {
            int col = w * 32 + ct * 16 + m;
            float bias = bc[col];
#pragma unroll
            for (int reg = 0; reg < 4; ++reg) {
                int row = rt * 16 + quad * 4 + reg;
                float val = fmaxf(acc[rt][ct][reg] + bias, 0.f);
                ob[row * Cn + col] = (unsigned short)f2bf(val);
            }
        }
}

// ---------------- general conv: hn = relu((A h) @ Wc + bc), uint4 gather (16 B/lane) ----------------
// thread map: c8 = tid&15 (channels c8*8..c8*8+7), u = tid>>4 (rows u*2, u*2+1)
__global__ __launch_bounds__(256, 4) void k_conv(const uint32_t* __restrict__ h,
                                                 unsigned short* __restrict__ hn,
                                                 const unsigned short* __restrict__ Wt,
                                                 const float* __restrict__ bc,
                                                 const int* __restrict__ offs,
                                                 const int* __restrict__ ssrc,
                                                 int swz) {
    __shared__ unsigned short sSb[32 * PAD];   // 8.7 KB
    __shared__ int sIdx[ECHUNK];               // 3 KB
    int tid = threadIdx.x, bidx = blockIdx.x;
    int b, dst0;
    if (swz) {
        int xcd = bidx & 7, q = bidx >> 3;
        b = xcd * 8 + (q >> 5);
        dst0 = (q & 31) * 32;
    } else {
        b = bidx >> 5;
        dst0 = (bidx & 31) * 32;
    }

    int c8 = tid & 15, u = tid >> 4;
    const uint4* hb4 = (const uint4*)(h + (size_t)b * (Nn * 64));
    float acc[2][8];
#pragma unroll
    for (int t0 = 0; t0 < 2; ++t0)
#pragma unroll
        for (int i = 0; i < 8; ++i) acc[t0][i] = 0.f;

    int e_begin = offs[dst0], e_end = offs[dst0 + 32];
    for (int base = e_begin; base < e_end; base += ECHUNK) {
        int cnt = e_end - base; if (cnt > ECHUNK) cnt = ECHUNK;
        __syncthreads();
        for (int i = tid; i < cnt; i += 256) sIdx[i] = ssrc[base + i];
        __syncthreads();
#pragma unroll
        for (int t0 = 0; t0 < 2; ++t0) {
            int dst = dst0 + u * 2 + t0;
            int lo = offs[dst], hi = offs[dst + 1];
            int j0 = (lo > base ? lo : base) - base;
            int j1 = ((hi < base + cnt) ? hi : base + cnt) - base;
            int j = j0;
            for (; j + 4 <= j1; j += 4) {
                uint4 v0 = hb4[sIdx[j + 0] * 16 + c8];
                uint4 v1 = hb4[sIdx[j + 1] * 16 + c8];
                uint4 v2 = hb4[sIdx[j + 2] * 16 + c8];
                uint4 v3 = hb4[sIdx[j + 3] * 16 + c8];
                acc[t0][0] += bflo(v0.x) + bflo(v1.x) + bflo(v2.x) + bflo(v3.x);
                acc[t0][1] += bfhi(v0.x) + bfhi(v1.x) + bfhi(v2.x) + bfhi(v3.x);
                acc[t0][2] += bflo(v0.y) + bflo(v1.y) + bflo(v2.y) + bflo(v3.y);
                acc[t0][3] += bfhi(v0.y) + bfhi(v1.y) + bfhi(v2.y) + bfhi(v3.y);
                acc[t0][4] += bflo(v0.z) + bflo(v1.z) + bflo(v2.z) + bflo(v3.z);
                acc[t0][5] += bfhi(v0.z) + bfhi(v1.z) + bfhi(v2.z) + bfhi(v3.z);
                acc[t0][6] += bflo(v0.w) + bflo(v1.w) + bflo(v2.w) + bflo(v3.w);
                acc[t0][7] += bfhi(v0.w) + bfhi(v1.w) + bfhi(v2.w) + bfhi(v3.w);
            }
            for (; j < j1; ++j) {
                uint4 v = hb4[sIdx[j] * 16 + c8];
                acc[t0][0] += bflo(v.x); acc[t0][1] += bfhi(v.x);
                acc[t0][2] += bflo(v.y); acc[t0][3] += bfhi(v.y);
                acc[t0][4] += bflo(v.z); acc[t0][5] += bfhi(v.z);
                acc[t0][6] += bflo(v.w); acc[t0][7] += bfhi(v.w);
            }
        }
    }
#pragma unroll
    for (int t0 = 0; t0 < 2; ++t0) {
        int row = u * 2 + t0;
        uint32_t p0 = f2bf(acc[t0][0]) | (f2bf(acc[t0][1]) << 16);
        uint32_t p1 = f2bf(acc[t0][2]) | (f2bf(acc[t0][3]) << 16);
        uint32_t p2 = f2bf(acc[t0][4]) | (f2bf(acc[t0][5]) << 16);
        uint32_t p3 = f2bf(acc[t0][6]) | (f2bf(acc[t0][7]) << 16);
        uint4 pk = {p0, p1, p2, p3};
        *(uint4*)&sSb[row * PAD + c8 * 8] = pk;
    }

    // B-fragments from global Wt (32 KB, L2-hot)
    int lane = tid & 63, w = tid >> 6;
    int m = lane & 15, quad = lane >> 4;
    s16x8 bf0[4], bf1[4];
#pragma unroll
    for (int ks = 0; ks < 4; ++ks) {
        int ko = ks * 32 + quad * 8;
        bf0[ks] = *(const s16x8*)&Wt[(w * 32 + m) * Cn + ko];
        bf1[ks] = *(const s16x8*)&Wt[(w * 32 + 16 + m) * Cn + ko];
    }
    __syncthreads();

    f32x4 accm[2][2];
#pragma unroll
    for (int rt = 0; rt < 2; ++rt)
#pragma unroll
        for (int ct = 0; ct < 2; ++ct) accm[rt][ct] = (f32x4){0.f, 0.f, 0.f, 0.f};
#pragma unroll
    for (int ks = 0; ks < 4; ++ks) {
        int ko = ks * 32 + quad * 8;
        s16x8 a0 = *(const s16x8*)&sSb[(0 * 16 + m) * PAD + ko];
        s16x8 a1 = *(const s16x8*)&sSb[(1 * 16 + m) * PAD + ko];
        accm[0][0] = __builtin_amdgcn_mfma_f32_16x16x32_bf16(a0, bf0[ks], accm[0][0], 0, 0, 0);
        accm[0][1] = __builtin_amdgcn_mfma_f32_16x16x32_bf16(a0, bf1[ks], accm[0][1], 0, 0, 0);
        accm[1][0] = __builtin_amdgcn_mfma_f32_16x16x32_bf16(a1, bf0[ks], accm[1][0], 0, 0, 0);
        accm[1][1] = __builtin_amdgcn_mfma_f32_16x16x32_bf16(a1, bf1[ks], accm[1][1], 0, 0, 0);
    }

    unsigned short* ob = hn + ((size_t)b * Nn + dst0) * Cn;
#pragma unroll
    for (int rt = 0; rt < 2; ++rt)
#pragma unroll
        for (int ct = 0; ct < 2; ++ct) {
            int col = w * 32 + ct * 16 + m;
            float bias = bc[col];
#pragma unroll
            for (int reg = 0; reg < 4; ++reg) {
                int row = rt * 16 + quad * 4 + reg;
                float val = fmaxf(accm[rt][ct][reg] + bias, 0.f);
                ob[row * Cn + col] = (unsigned short)f2bf(val);
            }
        }
}

// ---------------- classifier: out[b] = h_bf16[b*N + 0] . W_cls + b_cls ----------------
__global__ __launch_bounds__(128) void k_cls(const unsigned short* __restrict__ h,
                                             const float* __restrict__ Wcls,
                                             const float* __restrict__ bcls,
                                             float* __restrict__ out) {
    __shared__ float red[128];
    int b = blockIdx.x, t = threadIdx.x;
    float hv = __uint_as_float(((uint32_t)h[(size_t)b * Nn * Cn + t]) << 16);
    red[t] = hv * Wcls[t];
    __syncthreads();
    for (int s = 64; s > 0; s >>= 1) {
        if (t < s) red[t] += red[t + s];
        __syncthreads();
    }
    if (t == 0) out[b] = red[0] + bcls[0];
}

extern "C" void kernel_launch(void* const* d_in, const int* in_sizes, int n_in,
                              void* d_out, int out_size, void* d_ws, size_t ws_size,
                              hipStream_t stream) {
    const float* x    = (const float*)d_in[0];
    const int*   ei32 = (const int*)d_in[1];
    const float* We   = (const float*)d_in[2];
    const float* be   = (const float*)d_in[3];
    const float* Wc   = (const float*)d_in[4];
    const float* bc   = (const float*)d_in[5];
    const float* Wcls = (const float*)d_in[6];
    const float* bcls = (const float*)d_in[7];
    float* out = (float*)d_out;

    // ---- workspace layout ----
    // 0       g      32768   (B x C fp32)
    // 32768   indeg   4096
    // 36864   meta    4096   (meta[1] == 1 iff int32 edge data detected)
    // 40960   offs    8192
    // 49152   cursor  4096
    // 53248   ssrc   65536
    // 118784  Wt     32768   (128x128 bf16, transposed)
    // 151552  pws   131072   (embed partials)
    // 282624  heap: ping-pong bf16 h buffers
    constexpr size_t WS_FIXED = 282624;
    char* ws = (char*)d_ws;
    float*          g      = (float*)(ws + 0);
    int*            indeg  = (int*)(ws + 32768);
    int*            meta   = (int*)(ws + 36864);
    int*            offs   = (int*)(ws + 40960);
    int*            cursor = (int*)(ws + 49152);
    int*            ssrc   = (int*)(ws + 53248);
    unsigned short* Wt     = (unsigned short*)(ws + 118784);
    float*          pws    = (float*)(ws + 151552);

    size_t per = (size_t)Nn * Cn * 2;     // 256 KB per sample (bf16)
    size_t avail = (ws_size > WS_FIXED) ? (ws_size - WS_FIXED) : 0;
    int G = (int)(avail / (2 * per));
    if (G > Bn) G = Bn;
    if (G < 1) G = 1;
    unsigned short* hA = (unsigned short*)(ws + WS_FIXED);
    unsigned short* hB = hA + (size_t)G * Nn * Cn;

    k_prep<<<132, 256, 0, stream>>>(ei32, Wc, indeg, meta, Wt);
    k_hist<<<64, 256, 0, stream>>>(ei32, meta, indeg);
    k_scan<<<1, 1024, 0, stream>>>(indeg, offs, cursor);
    k_scatter<<<64, 256, 0, stream>>>(ei32, meta, cursor, ssrc);
    k_embedA<<<256, 256, 0, stream>>>(x, We, pws);
    k_g<<<64, 128, 0, stream>>>(pws, be, Wc, g);

    for (int b0 = 0; b0 < Bn; b0 += G) {
        int gc = (Bn - b0 < G) ? (Bn - b0) : G;
        int swz = (gc == 64) ? 1 : 0;
        // convs 1+2 fused (conv1 analytic: h1[src]=relu(indeg[src]*g+bc)); then convs 3,4
        k_conv2f<<<gc * 32, 256, 0, stream>>>(g + b0 * Cn, hA, Wt, bc, indeg, offs, ssrc, swz);
        k_conv<<<gc * 32, 256, 0, stream>>>((const uint32_t*)hA, hB, Wt, bc, offs, ssrc, swz);
        k_conv<<<gc * 32, 256, 0, stream>>>((const uint32_t*)hB, hA, Wt, bc, offs, ssrc, swz);
        k_cls<<<gc, 128, 0, stream>>>(hA, Wcls, bcls, out + b0);
    }
}